// Round 1
// baseline (114.662 us; speedup 1.0000x reference)
//
#include <hip/hip_runtime.h>
#include <math.h>

#define N_ROWS 4096
#define DIM 256
constexpr float INV_T = 10.0f;

typedef __attribute__((ext_vector_type(8))) short short8;   // bf16x8 MFMA operand
typedef __attribute__((ext_vector_type(4))) float floatx4;  // fp32x4 accumulator

__device__ __forceinline__ unsigned short f2bf(float f) {
    unsigned int u = __float_as_uint(f);
    unsigned int r = (u + 0x7FFFu + ((u >> 16) & 1u)) >> 16;  // round-nearest-even
    return (unsigned short)r;
}

// Kernel 1: one wave per row. Computes L2-normalized bf16 rows of z_j (-> R0)
// and z_i (-> R1), plus pos[r] = dot(zi_n, zj_n) * INV_T.
__global__ __launch_bounds__(256) void normalize_kernel(
    const float* __restrict__ z_i, const float* __restrict__ z_j,
    unsigned short* __restrict__ R0, unsigned short* __restrict__ R1,
    float* __restrict__ pos)
{
    int wave = threadIdx.x >> 6;
    int lane = threadIdx.x & 63;
    int row = blockIdx.x * 4 + wave;

    float4 a = ((const float4*)(z_i + (size_t)row * DIM))[lane];
    float4 b = ((const float4*)(z_j + (size_t)row * DIM))[lane];

    float ssa = a.x*a.x + a.y*a.y + a.z*a.z + a.w*a.w;
    float ssb = b.x*b.x + b.y*b.y + b.z*b.z + b.w*b.w;
    float dab = a.x*b.x + a.y*b.y + a.z*b.z + a.w*b.w;
    #pragma unroll
    for (int off = 1; off < 64; off <<= 1) {
        ssa += __shfl_xor(ssa, off);
        ssb += __shfl_xor(ssb, off);
        dab += __shfl_xor(dab, off);
    }
    float ra = rsqrtf(ssa);
    float rb = rsqrtf(ssb);

    ushort4 ua, ub;
    ua.x = f2bf(a.x * ra); ua.y = f2bf(a.y * ra); ua.z = f2bf(a.z * ra); ua.w = f2bf(a.w * ra);
    ub.x = f2bf(b.x * rb); ub.y = f2bf(b.y * rb); ub.z = f2bf(b.z * rb); ub.w = f2bf(b.w * rb);
    ((ushort4*)(R1 + (size_t)row * DIM))[lane] = ua;  // zi_norm -> rows n..2n-1
    ((ushort4*)(R0 + (size_t)row * DIM))[lane] = ub;  // zj_norm -> rows 0..n-1

    if (lane == 0) pos[row] = dab * ra * rb * INV_T;
}

// Kernel 2: fused S = R@R^T / T -> exp -> row-sum (diagonal excluded).
// 128x128 C-tile per block, 4 waves (2x2), 16x16x32 bf16 MFMA, K=256.
#define BM 128
#define BK 32
#define LDSS 40   // padded row stride in bf16 (80 B -> only 2-way bank aliasing, free)

__global__ __launch_bounds__(256) void gemm_expsum(
    const unsigned short* __restrict__ R0,
    const unsigned short* __restrict__ R1,
    float* __restrict__ denom)
{
    const unsigned short* R = blockIdx.z ? R1 : R0;
    float* den = denom + (size_t)blockIdx.z * N_ROWS;
    int rowTile = blockIdx.y * BM;
    int colTile = blockIdx.x * BM;

    __shared__ unsigned short As[BM * LDSS];
    __shared__ unsigned short Bs[BM * LDSS];

    int tid  = threadIdx.x;
    int lane = tid & 63;
    int wave = tid >> 6;
    int wy = wave >> 1, wx = wave & 1;
    int m = lane & 15, q = lane >> 4;

    floatx4 acc[4][4] = {};

    for (int k0 = 0; k0 < DIM; k0 += BK) {
        __syncthreads();
        #pragma unroll
        for (int r = 0; r < 2; ++r) {
            int idx = r * 256 + tid;
            int row = idx >> 2;
            int kc  = (idx & 3) * 8;
            uint4 va = *(const uint4*)(R + (size_t)(rowTile + row) * DIM + k0 + kc);
            *(uint4*)&As[row * LDSS + kc] = va;
            uint4 vb = *(const uint4*)(R + (size_t)(colTile + row) * DIM + k0 + kc);
            *(uint4*)&Bs[row * LDSS + kc] = vb;
        }
        __syncthreads();

        short8 af[4], bfr[4];
        #pragma unroll
        for (int t = 0; t < 4; ++t) {
            af[t]  = *(const short8*)&As[(wy * 64 + t * 16 + m) * LDSS + q * 8];
            bfr[t] = *(const short8*)&Bs[(wx * 64 + t * 16 + m) * LDSS + q * 8];
        }
        #pragma unroll
        for (int i = 0; i < 4; ++i)
            #pragma unroll
            for (int j = 0; j < 4; ++j)
                acc[i][j] = __builtin_amdgcn_mfma_f32_16x16x32_bf16(af[i], bfr[j], acc[i][j], 0, 0, 0);
    }

    // Epilogue: C/D layout col = lane&15, row = (lane>>4)*4 + reg (m89/m91).
    #pragma unroll
    for (int i = 0; i < 4; ++i) {
        int growBase = rowTile + wy * 64 + i * 16;
        float rs[4] = {0.f, 0.f, 0.f, 0.f};
        #pragma unroll
        for (int j = 0; j < 4; ++j) {
            int gcol = colTile + wx * 64 + j * 16 + m;
            #pragma unroll
            for (int r = 0; r < 4; ++r) {
                int grow = growBase + q * 4 + r;
                float s = acc[i][j][r] * INV_T;
                float e = (grow == gcol) ? 0.0f : __expf(s);
                rs[r] += e;
            }
        }
        #pragma unroll
        for (int off = 1; off < 16; off <<= 1) {
            #pragma unroll
            for (int r = 0; r < 4; ++r) rs[r] += __shfl_xor(rs[r], off);
        }
        if (m == 0) {
            #pragma unroll
            for (int r = 0; r < 4; ++r)
                atomicAdd(&den[growBase + q * 4 + r], rs[r]);
        }
    }
}

// Kernel 3: loss = mean over 2n rows of log(denom + exp(pos)) - pos.
__global__ __launch_bounds__(256) void finalize_kernel(
    const float* __restrict__ denom, const float* __restrict__ pos,
    float* __restrict__ out)
{
    float s = 0.f;
    for (int r = threadIdx.x; r < 2 * N_ROWS; r += 256) {
        float p = pos[r & (N_ROWS - 1)];
        s += logf(denom[r] + __expf(p)) - p;
    }
    #pragma unroll
    for (int off = 1; off < 64; off <<= 1) s += __shfl_xor(s, off);
    __shared__ float red[4];
    int lane = threadIdx.x & 63, wave = threadIdx.x >> 6;
    if (lane == 0) red[wave] = s;
    __syncthreads();
    if (threadIdx.x == 0)
        out[0] = (red[0] + red[1] + red[2] + red[3]) / (2.0f * N_ROWS);
}

extern "C" void kernel_launch(void* const* d_in, const int* in_sizes, int n_in,
                              void* d_out, int out_size, void* d_ws, size_t ws_size,
                              hipStream_t stream) {
    const float* z_i = (const float*)d_in[0];
    const float* z_j = (const float*)d_in[1];
    char* ws = (char*)d_ws;
    unsigned short* R0 = (unsigned short*)ws;                         // zj_norm bf16, 2 MB
    unsigned short* R1 = (unsigned short*)(ws + (2u << 20));          // zi_norm bf16, 2 MB
    float* pos   = (float*)(ws + (4u << 20));                         // 16 KB
    float* denom = (float*)(ws + (4u << 20) + (64u << 10));           // 32 KB

    hipMemsetAsync(denom, 0, 2 * N_ROWS * sizeof(float), stream);
    normalize_kernel<<<N_ROWS / 4, 256, 0, stream>>>(z_i, z_j, R0, R1, pos);
    dim3 grid(N_ROWS / BM, N_ROWS / BM, 2);
    gemm_expsum<<<grid, 256, 0, stream>>>(R0, R1, denom);
    finalize_kernel<<<1, 256, 0, stream>>>(denom, pos, (float*)d_out);
}